// Round 2
// baseline (725.103 us; speedup 1.0000x reference)
//
#include <hip/hip_runtime.h>
#include <hip/hip_fp16.h>

#define N_NODES 100000
#define N_EDGES 3200000
#define IN_DIM  512
#define HID_DIM 16

#define B_BKT   782      // ceil(100000 / 128) buckets of 128 nodes
#define BKT_SH  7        // bucket = dst >> 7, dstrel = dst & 127
#define EPB     12500    // edges per s1 block (256 blocks * 12500 = 3.2M)
#define CAP_MAX 4608     // per-bucket record capacity (mean 4093 + ~8 sigma)

#define G1_TILES 6250    // 100000 / 16 rows per MFMA tile (exact)

typedef __attribute__((ext_vector_type(8))) short bf16x8;
typedef __attribute__((ext_vector_type(4))) float f32x4;

__device__ __forceinline__ void atomic_add_f32(float* p, float v) {
    __hip_atomic_fetch_add(p, v, __ATOMIC_RELAXED, __HIP_MEMORY_SCOPE_AGENT);
}
__device__ __forceinline__ int atomic_add_i32(int* p, int v) {
    return __hip_atomic_fetch_add(p, v, __ATOMIC_RELAXED, __HIP_MEMORY_SCOPE_AGENT);
}

__device__ __forceinline__ unsigned short bf16_rne(float f) {
    unsigned u = __float_as_uint(f);
    return (unsigned short)((u + 0x7fffu + ((u >> 16) & 1u)) >> 16);
}

// ---------------------------------------------------------------------------
__global__ void z0_init(int* __restrict__ cursor, int cap) {
    int b = blockIdx.x * blockDim.x + threadIdx.x;
    if (b < B_BKT) cursor[b] = b * cap;
}

// ---------------------------------------------------------------------------
// g1: xw = x @ W1 via MFMA (split-bf16 for fp32-equivalent precision).
// One wave per 16-row tile. A fragment (x) loaded DIRECTLY from global:
// lane l reads x[row0 + (l&15)][c*32 + 8*(l>>4) .. +7] = contiguous 32B,
// 128B-aligned per (row, kgroup) -> fully coalesced, no LDS staging for x.
// W1 pre-split into bf16 hi/lo fragments in LDS once per block (32 KB).
// D = Ah*Bh + Al*Bh + Ah*Bl (fp32 acc); dropped Al*Bl term ~1e-5 abs.
// C/D layout (m89-verified): col = lane&15, row = 4*(lane>>4) + i.
__global__ __launch_bounds__(256) void g1_xw_mfma(const float* __restrict__ x,
                                                  const float* __restrict__ W1,
                                                  __half* __restrict__ xwh) {
    __shared__ alignas(16) unsigned short whi[16 * 64 * 8];
    __shared__ alignas(16) unsigned short wlo[16 * 64 * 8];
    const int t = threadIdx.x;

    // Stage W1 fragments: idx = c*512 + lane*8 + tt
    //   k = c*32 + (lane>>4)*8 + tt,  j = lane&15  (B[k][n]: n=lane&15)
    for (int idx = t; idx < 16 * 64 * 8; idx += 256) {
        int c  = idx >> 9;
        int l  = (idx >> 3) & 63;
        int tt = idx & 7;
        int k  = c * 32 + ((l >> 4) << 3) + tt;
        int j  = l & 15;
        float w = W1[k * HID_DIM + j];
        unsigned u = __float_as_uint(w);
        float hif = __uint_as_float(u & 0xffff0000u);   // truncated bf16 as f32
        whi[idx] = (unsigned short)(u >> 16);
        wlo[idx] = bf16_rne(w - hif);                   // residual, RNE bf16
    }
    __syncthreads();

    const int lane = t & 63;
    const int wid  = blockIdx.x * 4 + (t >> 6);         // tile id
    if (wid >= G1_TILES) return;
    const int row0 = wid * 16;

    const float* xrow = x + (size_t)(row0 + (lane & 15)) * IN_DIM + ((lane >> 4) << 3);
    const unsigned short* whp = &whi[lane * 8];
    const unsigned short* wlp = &wlo[lane * 8];

    f32x4 acc = {0.f, 0.f, 0.f, 0.f};
    float4 a0 = *(const float4*)(xrow);
    float4 a1 = *(const float4*)(xrow + 4);
#pragma unroll
    for (int c = 0; c < 16; ++c) {
        float4 n0, n1;
        if (c < 15) {                                   // 1-chunk register prefetch
            n0 = *(const float4*)(xrow + (c + 1) * 32);
            n1 = *(const float4*)(xrow + (c + 1) * 32 + 4);
        }
        float av[8] = {a0.x, a0.y, a0.z, a0.w, a1.x, a1.y, a1.z, a1.w};
        bf16x8 ah, al;
#pragma unroll
        for (int e = 0; e < 8; ++e) {
            unsigned u = __float_as_uint(av[e]);
            ah[e] = (short)(u >> 16);                   // truncated bf16 hi
            float lof = av[e] - __uint_as_float(u & 0xffff0000u);
            al[e] = (short)bf16_rne(lof);               // residual lo
        }
        bf16x8 bh = *(const bf16x8*)(whp + (size_t)c * 512);
        bf16x8 bl = *(const bf16x8*)(wlp + (size_t)c * 512);
        acc = __builtin_amdgcn_mfma_f32_16x16x32_bf16(ah, bh, acc, 0, 0, 0);
        acc = __builtin_amdgcn_mfma_f32_16x16x32_bf16(al, bh, acc, 0, 0, 0);
        acc = __builtin_amdgcn_mfma_f32_16x16x32_bf16(ah, bl, acc, 0, 0, 0);
        a0 = n0; a1 = n1;
    }

    const int n     = lane & 15;
    const int rbase = row0 + ((lane >> 4) << 2);
#pragma unroll
    for (int i = 0; i < 4; ++i)
        xwh[(size_t)(rbase + i) * HID_DIM + n] = __float2half_rn(acc[i]);
}

// ---------------------------------------------------------------------------
// s1: counting-sort edges into coarse bucket regions, block-batched runs.
__global__ __launch_bounds__(1024) void s1_bin(const int* __restrict__ src,
                                               const int* __restrict__ dst,
                                               const float* __restrict__ wgt,
                                               int* __restrict__ cursor,
                                               uint2* __restrict__ rec, int cap) {
    __shared__ int hist[B_BKT];
    __shared__ int base[B_BKT];
    const int t = threadIdx.x;
    for (int b = t; b < B_BKT; b += 1024) hist[b] = 0;
    __syncthreads();
    const int e0 = blockIdx.x * EPB;
    const int4*   d4 = (const int4*)(dst + e0);
    const int4*   s4 = (const int4*)(src + e0);
    const float4* w4 = (const float4*)(wgt + e0);
    const int NG = EPB / 4;
    for (int g = t; g < NG; g += 1024) {
        int4 d = d4[g];
        atomicAdd(&hist[d.x >> BKT_SH], 1);
        atomicAdd(&hist[d.y >> BKT_SH], 1);
        atomicAdd(&hist[d.z >> BKT_SH], 1);
        atomicAdd(&hist[d.w >> BKT_SH], 1);
    }
    __syncthreads();
    for (int b = t; b < B_BKT; b += 1024) {
        int c = hist[b];
        base[b] = c > 0 ? atomic_add_i32(&cursor[b], c) : 0;
    }
    __syncthreads();
    for (int b = t; b < B_BKT; b += 1024) hist[b] = 0;
    __syncthreads();
    for (int g = t; g < NG; g += 1024) {
        int4 d = d4[g];
        int4 s = s4[g];
        float4 w = w4[g];
        {
            int b = d.x >> BKT_SH;
            int pos = base[b] + atomicAdd(&hist[b], 1);
            rec[pos] = make_uint2(((unsigned)s.x << BKT_SH) | (unsigned)(d.x & 127),
                                  __float_as_uint(w.x));
        }
        {
            int b = d.y >> BKT_SH;
            int pos = base[b] + atomicAdd(&hist[b], 1);
            rec[pos] = make_uint2(((unsigned)s.y << BKT_SH) | (unsigned)(d.y & 127),
                                  __float_as_uint(w.y));
        }
        {
            int b = d.z >> BKT_SH;
            int pos = base[b] + atomicAdd(&hist[b], 1);
            rec[pos] = make_uint2(((unsigned)s.z << BKT_SH) | (unsigned)(d.z & 127),
                                  __float_as_uint(w.z));
        }
        {
            int b = d.w >> BKT_SH;
            int pos = base[b] + atomicAdd(&hist[b], 1);
            rec[pos] = make_uint2(((unsigned)s.w << BKT_SH) | (unsigned)(d.w & 127),
                                  __float_as_uint(w.w));
        }
    }
}

// ---------------------------------------------------------------------------
// p4b: fused (bucket-local spmm1) + bias + relu + (.W2) — NO pre-sort needed.
// One block per bucket; 16 lanes per edge (lane j owns dim j); ds_add_f32
// into swizzled h[128][16] LDS tile. Swizzle (d<<4)|((j+d)&15): one edge's
// 16 adds hit 16 distinct banks, even/odd d cover all 32 -> conflict-free.
// Replaces s2_sort + p4_layer1: rec is written once (s1) and read once here.
__global__ __launch_bounds__(512) void p4_bucket(const int* __restrict__ cursor,
                                                 const uint2* __restrict__ rec,
                                                 const __half* __restrict__ xwh,
                                                 const float* __restrict__ b1,
                                                 const float* __restrict__ W2,
                                                 float* __restrict__ hw, int cap) {
    __shared__ float h[128 * 16];
    const int t = threadIdx.x;
    const int bkt = blockIdx.x;
    const int e0 = bkt * cap;
    int n = cursor[bkt] - e0;
    n = max(0, min(n, cap));
    for (int i = t; i < 128 * 16; i += 512) h[i] = 0.0f;
    __syncthreads();
    const int j = t & 15;
    for (int i = (t >> 4); i < n; i += 32) {
        uint2 r = rec[e0 + i];
        int   d = (int)(r.x & 127u);
        int   s = (int)(r.x >> BKT_SH);
        float w = __uint_as_float(r.y);
        float f = __half2float(xwh[(size_t)s * HID_DIM + j]);
        atomicAdd(&h[(d << 4) | ((j + d) & 15)], w * f);
    }
    __syncthreads();
    if (t < 128) {
        int node = (bkt << BKT_SH) + t;
        if (node < N_NODES) {
            float v = 0.0f;
#pragma unroll
            for (int jj = 0; jj < 16; ++jj)
                v += fmaxf(h[(t << 4) | ((jj + t) & 15)] + b1[jj], 0.0f) * W2[jj];
            hw[node] = v;
        }
    }
}

// ---------------------------------------------------------------------------
// p5b: bucket-local spmm2. One lane per edge, one ds_add_f32 into o[128].
__global__ __launch_bounds__(512) void p5_bucket(const int* __restrict__ cursor,
                                                 const uint2* __restrict__ rec,
                                                 const float* __restrict__ hwv,
                                                 const float* __restrict__ b2,
                                                 float* __restrict__ out, int cap) {
    __shared__ float o[128];
    const int t = threadIdx.x;
    const int bkt = blockIdx.x;
    const int e0 = bkt * cap;
    int n = cursor[bkt] - e0;
    n = max(0, min(n, cap));
    if (t < 128) o[t] = 0.0f;
    __syncthreads();
    for (int i = t; i < n; i += 512) {
        uint2 r = rec[e0 + i];
        atomicAdd(&o[r.x & 127u], __uint_as_float(r.y) * hwv[r.x >> BKT_SH]);
    }
    __syncthreads();
    if (t < 128) {
        int node = (bkt << BKT_SH) + t;
        if (node < N_NODES) out[node] = b2[0] + o[t];
    }
}

// ---------------------------------------------------------------------------
// fallback path (atomic scatter) if workspace is too small
// ---------------------------------------------------------------------------
__global__ void f0_zero(float* __restrict__ h, const float* __restrict__ b2,
                        float* __restrict__ out) {
    int i = blockIdx.x * blockDim.x + threadIdx.x;
    if (i < N_NODES * HID_DIM) h[i] = 0.0f;
    if (i < N_NODES) out[i] = b2[0];
}
__global__ void k2_spmm1(const int* __restrict__ src, const int* __restrict__ dst,
                         const float* __restrict__ wgt, const __half* __restrict__ xwh,
                         float* __restrict__ h) {
    int t = blockIdx.x * blockDim.x + threadIdx.x;
    int e = t >> 4;
    int j = t & (HID_DIM - 1);
    if (e < N_EDGES) {
        float v = wgt[e] * __half2float(xwh[(size_t)src[e] * HID_DIM + j]);
        atomic_add_f32(&h[(size_t)dst[e] * HID_DIM + j], v);
    }
}
__global__ void k3_act(const float* __restrict__ h, const float* __restrict__ b1,
                       const float* __restrict__ W2, float* __restrict__ hw) {
    int i = blockIdx.x * blockDim.x + threadIdx.x;
    if (i >= N_NODES) return;
    const float4* h4 = (const float4*)(h + (size_t)i * HID_DIM);
    const float4* b4 = (const float4*)b1;
    const float4* w4 = (const float4*)W2;
    float acc = 0.0f;
#pragma unroll
    for (int q = 0; q < HID_DIM / 4; ++q) {
        float4 hv = h4[q]; float4 bv = b4[q]; float4 wv = w4[q];
        acc += fmaxf(hv.x + bv.x, 0.0f) * wv.x;
        acc += fmaxf(hv.y + bv.y, 0.0f) * wv.y;
        acc += fmaxf(hv.z + bv.z, 0.0f) * wv.z;
        acc += fmaxf(hv.w + bv.w, 0.0f) * wv.w;
    }
    hw[i] = acc;
}
__global__ void k4_spmm2(const int* __restrict__ src, const int* __restrict__ dst,
                         const float* __restrict__ wgt, const float* __restrict__ hw,
                         float* __restrict__ out) {
    int e = blockIdx.x * blockDim.x + threadIdx.x;
    if (e < N_EDGES) atomic_add_f32(&out[dst[e]], wgt[e] * hw[src[e]]);
}

// ---------------------------------------------------------------------------

extern "C" void kernel_launch(void* const* d_in, const int* in_sizes, int n_in,
                              void* d_out, int out_size, void* d_ws, size_t ws_size,
                              hipStream_t stream) {
    const float* x    = (const float*)d_in[0];
    const int*   esrc = (const int*)  d_in[1];
    const int*   edst = (const int*)  d_in[2];
    const float* ew   = (const float*)d_in[3];
    const float* W1   = (const float*)d_in[4];
    const float* b1   = (const float*)d_in[5];
    const float* W2   = (const float*)d_in[6];
    const float* b2   = (const float*)d_in[7];
    float* out = (float*)d_out;
    char* ws = (char*)d_ws;

    // workspace layout
    __half* xwh    = (__half*)ws;                                  // N*16 halfs
    float*  hw     = (float*)(ws + (size_t)N_NODES * HID_DIM * 2); // N floats
    int*    cursor = (int*)(hw + N_NODES);                         // B_BKT ints
    size_t rec_off = ((size_t)((char*)(cursor + B_BKT) - ws) + 15) & ~(size_t)15;
    uint2* rec = (uint2*)(ws + rec_off);

    int cap = 0;
    if (ws_size > rec_off) {
        size_t cap_fit = (ws_size - rec_off) / ((size_t)B_BKT * sizeof(uint2));
        cap = (int)(cap_fit < CAP_MAX ? cap_fit : CAP_MAX);
    }

    if (cap >= 4480) {
        z0_init<<<(B_BKT + 255) / 256, 256, 0, stream>>>(cursor, cap);
        g1_xw_mfma<<<(G1_TILES + 3) / 4, 256, 0, stream>>>(x, W1, xwh);
        s1_bin<<<N_EDGES / EPB, 1024, 0, stream>>>(esrc, edst, ew, cursor, rec, cap);
        p4_bucket<<<B_BKT, 512, 0, stream>>>(cursor, rec, xwh, b1, W2, hw, cap);
        p5_bucket<<<B_BKT, 512, 0, stream>>>(cursor, rec, hw, b2, out, cap);
    } else {
        // fallback: atomic scatter
        __half* f_xwh = (__half*)ws;
        float*  f_h   = (float*)(ws + (size_t)N_NODES * HID_DIM * 2);
        float*  f_hw  = f_h + (size_t)N_NODES * HID_DIM;
        int n = N_NODES * HID_DIM;
        f0_zero<<<(n + 255) / 256, 256, 0, stream>>>(f_h, b2, out);
        g1_xw_mfma<<<(G1_TILES + 3) / 4, 256, 0, stream>>>(x, W1, f_xwh);
        k2_spmm1<<<(N_EDGES * 16) / 256, 256, 0, stream>>>(esrc, edst, ew, f_xwh, f_h);
        k3_act<<<(N_NODES + 255) / 256, 256, 0, stream>>>(f_h, b1, W2, f_hw);
        k4_spmm2<<<(N_EDGES + 255) / 256, 256, 0, stream>>>(esrc, edst, ew, f_hw, out);
    }
}

// Round 3
// 443.241 us; speedup vs baseline: 1.6359x; 1.6359x over previous
//
#include <hip/hip_runtime.h>
#include <hip/hip_fp16.h>

#define N_NODES 100000
#define N_EDGES 3200000
#define IN_DIM  512
#define HID_DIM 16

#define B_BKT   782      // ceil(100000 / 128) buckets of 128 nodes
#define BKT_SH  7        // bucket = dst >> 7, dstrel = dst & 127
#define EPB     12500    // edges per s1 block (256 blocks * 12500 = 3.2M)
#define CAP_MAX 4608     // per-bucket record capacity (mean 4093 + ~8 sigma)

#define G1_TILES 6250    // 100000 / 16 rows per MFMA tile (exact)

typedef __attribute__((ext_vector_type(8))) short bf16x8;
typedef __attribute__((ext_vector_type(4))) float f32x4;

__device__ __forceinline__ void atomic_add_f32(float* p, float v) {
    __hip_atomic_fetch_add(p, v, __ATOMIC_RELAXED, __HIP_MEMORY_SCOPE_AGENT);
}
__device__ __forceinline__ int atomic_add_i32(int* p, int v) {
    return __hip_atomic_fetch_add(p, v, __ATOMIC_RELAXED, __HIP_MEMORY_SCOPE_AGENT);
}

__device__ __forceinline__ unsigned short bf16_rne(float f) {
    unsigned u = __float_as_uint(f);
    return (unsigned short)((u + 0x7fffu + ((u >> 16) & 1u)) >> 16);
}

// ---------------------------------------------------------------------------
__global__ void z0_init(int* __restrict__ cursor, int cap) {
    int b = blockIdx.x * blockDim.x + threadIdx.x;
    if (b < B_BKT) cursor[b] = b * cap;
}

// ---------------------------------------------------------------------------
// g1: xw = x @ W1 via MFMA (split-bf16 for fp32-equivalent precision).
// One wave per 16-row tile. A fragment (x) loaded DIRECTLY from global:
// lane l reads x[row0 + (l&15)][c*32 + 8*(l>>4) .. +7] = contiguous 32B,
// fully coalesced, no LDS staging for x. W1 pre-split into bf16 hi/lo
// fragments in LDS once per block (32 KB).
// D = Ah*Bh + Al*Bh + Ah*Bl (fp32 acc); dropped Al*Bl term ~1e-5 abs.
// C/D layout (m89-verified): col = lane&15, row = 4*(lane>>4) + i.
// R3 change: register prefetch depth 2 (4 dwordx4 in flight per wave) —
// depth 1 left the wave stalling ~900cy HBM latency per 60cy of compute.
__global__ __launch_bounds__(256) void g1_xw_mfma(const float* __restrict__ x,
                                                  const float* __restrict__ W1,
                                                  __half* __restrict__ xwh) {
    __shared__ alignas(16) unsigned short whi[16 * 64 * 8];
    __shared__ alignas(16) unsigned short wlo[16 * 64 * 8];
    const int t = threadIdx.x;

    // Stage W1 fragments: idx = c*512 + lane*8 + tt
    //   k = c*32 + (lane>>4)*8 + tt,  j = lane&15  (B[k][n]: n=lane&15)
    for (int idx = t; idx < 16 * 64 * 8; idx += 256) {
        int c  = idx >> 9;
        int l  = (idx >> 3) & 63;
        int tt = idx & 7;
        int k  = c * 32 + ((l >> 4) << 3) + tt;
        int j  = l & 15;
        float w = W1[k * HID_DIM + j];
        unsigned u = __float_as_uint(w);
        float hif = __uint_as_float(u & 0xffff0000u);   // truncated bf16 as f32
        whi[idx] = (unsigned short)(u >> 16);
        wlo[idx] = bf16_rne(w - hif);                   // residual, RNE bf16
    }
    __syncthreads();

    const int lane = t & 63;
    const int wid  = blockIdx.x * 4 + (t >> 6);         // tile id
    if (wid >= G1_TILES) return;
    const int row0 = wid * 16;

    const float* xrow = x + (size_t)(row0 + (lane & 15)) * IN_DIM + ((lane >> 4) << 3);
    const unsigned short* whp = &whi[lane * 8];
    const unsigned short* wlp = &wlo[lane * 8];

    f32x4 acc = {0.f, 0.f, 0.f, 0.f};
    float4 p0[2], p1[2];                                // 2-deep ring buffer
    p0[0] = *(const float4*)(xrow);
    p1[0] = *(const float4*)(xrow + 4);
    p0[1] = *(const float4*)(xrow + 32);
    p1[1] = *(const float4*)(xrow + 36);
#pragma unroll
    for (int c = 0; c < 16; ++c) {
        const int cur = c & 1;                          // static after unroll
        float4 n0, n1;
        if (c < 14) {                                   // prefetch chunk c+2
            n0 = *(const float4*)(xrow + (c + 2) * 32);
            n1 = *(const float4*)(xrow + (c + 2) * 32 + 4);
        }
        float av[8] = {p0[cur].x, p0[cur].y, p0[cur].z, p0[cur].w,
                       p1[cur].x, p1[cur].y, p1[cur].z, p1[cur].w};
        bf16x8 ah, al;
#pragma unroll
        for (int e = 0; e < 8; ++e) {
            unsigned u = __float_as_uint(av[e]);
            ah[e] = (short)(u >> 16);                   // truncated bf16 hi
            float lof = av[e] - __uint_as_float(u & 0xffff0000u);
            al[e] = (short)bf16_rne(lof);               // residual lo
        }
        bf16x8 bh = *(const bf16x8*)(whp + (size_t)c * 512);
        bf16x8 bl = *(const bf16x8*)(wlp + (size_t)c * 512);
        acc = __builtin_amdgcn_mfma_f32_16x16x32_bf16(ah, bh, acc, 0, 0, 0);
        acc = __builtin_amdgcn_mfma_f32_16x16x32_bf16(al, bh, acc, 0, 0, 0);
        acc = __builtin_amdgcn_mfma_f32_16x16x32_bf16(ah, bl, acc, 0, 0, 0);
        if (c < 14) { p0[cur] = n0; p1[cur] = n1; }
    }

    const int n     = lane & 15;
    const int rbase = row0 + ((lane >> 4) << 2);
#pragma unroll
    for (int i = 0; i < 4; ++i)
        xwh[(size_t)(rbase + i) * HID_DIM + n] = __float2half_rn(acc[i]);
}

// ---------------------------------------------------------------------------
// s1: counting-sort edges into coarse bucket regions, block-batched runs.
__global__ __launch_bounds__(1024) void s1_bin(const int* __restrict__ src,
                                               const int* __restrict__ dst,
                                               const float* __restrict__ wgt,
                                               int* __restrict__ cursor,
                                               uint2* __restrict__ rec, int cap) {
    __shared__ int hist[B_BKT];
    __shared__ int base[B_BKT];
    const int t = threadIdx.x;
    for (int b = t; b < B_BKT; b += 1024) hist[b] = 0;
    __syncthreads();
    const int e0 = blockIdx.x * EPB;
    const int4*   d4 = (const int4*)(dst + e0);
    const int4*   s4 = (const int4*)(src + e0);
    const float4* w4 = (const float4*)(wgt + e0);
    const int NG = EPB / 4;
    for (int g = t; g < NG; g += 1024) {
        int4 d = d4[g];
        atomicAdd(&hist[d.x >> BKT_SH], 1);
        atomicAdd(&hist[d.y >> BKT_SH], 1);
        atomicAdd(&hist[d.z >> BKT_SH], 1);
        atomicAdd(&hist[d.w >> BKT_SH], 1);
    }
    __syncthreads();
    for (int b = t; b < B_BKT; b += 1024) {
        int c = hist[b];
        base[b] = c > 0 ? atomic_add_i32(&cursor[b], c) : 0;
    }
    __syncthreads();
    for (int b = t; b < B_BKT; b += 1024) hist[b] = 0;
    __syncthreads();
    for (int g = t; g < NG; g += 1024) {
        int4 d = d4[g];
        int4 s = s4[g];
        float4 w = w4[g];
        {
            int b = d.x >> BKT_SH;
            int pos = base[b] + atomicAdd(&hist[b], 1);
            rec[pos] = make_uint2(((unsigned)s.x << BKT_SH) | (unsigned)(d.x & 127),
                                  __float_as_uint(w.x));
        }
        {
            int b = d.y >> BKT_SH;
            int pos = base[b] + atomicAdd(&hist[b], 1);
            rec[pos] = make_uint2(((unsigned)s.y << BKT_SH) | (unsigned)(d.y & 127),
                                  __float_as_uint(w.y));
        }
        {
            int b = d.z >> BKT_SH;
            int pos = base[b] + atomicAdd(&hist[b], 1);
            rec[pos] = make_uint2(((unsigned)s.z << BKT_SH) | (unsigned)(d.z & 127),
                                  __float_as_uint(w.z));
        }
        {
            int b = d.w >> BKT_SH;
            int pos = base[b] + atomicAdd(&hist[b], 1);
            rec[pos] = make_uint2(((unsigned)s.w << BKT_SH) | (unsigned)(d.w & 127),
                                  __float_as_uint(w.w));
        }
    }
}

// ---------------------------------------------------------------------------
// s2: per-bucket counting sort by dstrel, IN PLACE (recs staged in LDS).
// Emits row[node] = (segment begin, degree); rec becomes (src, w) by dst.
__global__ __launch_bounds__(512) void s2_sort(const int* __restrict__ cursor,
                                               uint2* __restrict__ rec,
                                               int2* __restrict__ row, int cap) {
    __shared__ uint2 srec[CAP_MAX];
    __shared__ int ocnt[128], scn[128], cur[128];
    const int t = threadIdx.x;
    const int bkt = blockIdx.x;
    const int e0 = bkt * cap;
    int n = cursor[bkt] - e0;
    n = max(0, min(n, cap));
    if (t < 128) ocnt[t] = 0;
    __syncthreads();
    for (int i = t; i < n; i += 512) {
        uint2 r = rec[e0 + i];
        srec[i] = r;
        atomicAdd(&ocnt[r.x & 127u], 1);
    }
    __syncthreads();
    if (t < 128) scn[t] = ocnt[t];
    __syncthreads();
    for (int off = 1; off < 128; off <<= 1) {
        int v = 0;
        if (t < 128 && t >= off) v = scn[t - off];
        __syncthreads();
        if (t < 128 && t >= off) scn[t] += v;
        __syncthreads();
    }
    if (t < 128) {
        int b = scn[t] - ocnt[t];          // exclusive prefix
        cur[t] = b;
        int node = (bkt << BKT_SH) + t;
        if (node < N_NODES) row[node] = make_int2(e0 + b, ocnt[t]);
    }
    __syncthreads();
    for (int i = t; i < n; i += 512) {
        uint2 r = srec[i];
        int d = (int)(r.x & 127u);
        int pos = atomicAdd(&cur[d], 1);
        rec[e0 + pos] = make_uint2(r.x >> BKT_SH, r.y);   // (src, w)
    }
}

// ---------------------------------------------------------------------------
// p4: fused spmm1 + bias + relu + (.W2). 16 lanes per node, lane j owns dim j.
// Register accumulation, no atomics.
__global__ __launch_bounds__(256) void p4_layer1(const int2* __restrict__ row,
                                                 const uint2* __restrict__ rec,
                                                 const __half* __restrict__ xwh,
                                                 const float* __restrict__ b1,
                                                 const float* __restrict__ W2,
                                                 float* __restrict__ hw) {
    const int t = threadIdx.x;
    const int node = blockIdx.x * 16 + (t >> 4);
    const int j = t & 15;
    int2 r = row[node];
    int e = r.x;
    const int end = r.x + r.y;
    float acc = 0.0f;
    for (; e + 4 <= end; e += 4) {
        uint2 q0 = rec[e], q1 = rec[e + 1], q2 = rec[e + 2], q3 = rec[e + 3];
        float f0 = __half2float(xwh[(size_t)q0.x * HID_DIM + j]);
        float f1 = __half2float(xwh[(size_t)q1.x * HID_DIM + j]);
        float f2 = __half2float(xwh[(size_t)q2.x * HID_DIM + j]);
        float f3 = __half2float(xwh[(size_t)q3.x * HID_DIM + j]);
        acc += __uint_as_float(q0.y) * f0;
        acc += __uint_as_float(q1.y) * f1;
        acc += __uint_as_float(q2.y) * f2;
        acc += __uint_as_float(q3.y) * f3;
    }
    for (; e < end; ++e) {
        uint2 q = rec[e];
        acc += __uint_as_float(q.y) * __half2float(xwh[(size_t)q.x * HID_DIM + j]);
    }
    float v = fmaxf(acc + b1[j], 0.0f) * W2[j];
    v += __shfl_xor(v, 1);
    v += __shfl_xor(v, 2);
    v += __shfl_xor(v, 4);
    v += __shfl_xor(v, 8);
    if (j == 0) hw[node] = v;
}

// ---------------------------------------------------------------------------
// p5: spmm2 over the same sorted records; 8 lanes/node, coalesced rec reads.
__global__ __launch_bounds__(256) void p5_layer2(const int2* __restrict__ row,
                                                 const uint2* __restrict__ rec,
                                                 const float* __restrict__ hwv,
                                                 const float* __restrict__ b2,
                                                 float* __restrict__ out) {
    const int t = threadIdx.x;
    const int node = blockIdx.x * 32 + (t >> 3);
    const int i = t & 7;
    int2 r = row[node];
    const int end = r.x + r.y;
    int k = r.x + i;
    float s = 0.0f;
    for (; k + 24 < end; k += 32) {
        uint2 a = rec[k], b = rec[k + 8], c = rec[k + 16], d = rec[k + 24];
        float ha = hwv[a.x], hb = hwv[b.x], hc = hwv[c.x], hd = hwv[d.x];
        s += __uint_as_float(a.y) * ha + __uint_as_float(b.y) * hb
           + __uint_as_float(c.y) * hc + __uint_as_float(d.y) * hd;
    }
    for (; k < end; k += 8) {
        uint2 a = rec[k];
        s += __uint_as_float(a.y) * hwv[a.x];
    }
    s += __shfl_xor(s, 1);
    s += __shfl_xor(s, 2);
    s += __shfl_xor(s, 4);
    if (i == 0) out[node] = b2[0] + s;
}

// ---------------------------------------------------------------------------
// fallback path (atomic scatter) if workspace is too small
// ---------------------------------------------------------------------------
__global__ void f0_zero(float* __restrict__ h, const float* __restrict__ b2,
                        float* __restrict__ out) {
    int i = blockIdx.x * blockDim.x + threadIdx.x;
    if (i < N_NODES * HID_DIM) h[i] = 0.0f;
    if (i < N_NODES) out[i] = b2[0];
}
__global__ void k2_spmm1(const int* __restrict__ src, const int* __restrict__ dst,
                         const float* __restrict__ wgt, const __half* __restrict__ xwh,
                         float* __restrict__ h) {
    int t = blockIdx.x * blockDim.x + threadIdx.x;
    int e = t >> 4;
    int j = t & (HID_DIM - 1);
    if (e < N_EDGES) {
        float v = wgt[e] * __half2float(xwh[(size_t)src[e] * HID_DIM + j]);
        atomic_add_f32(&h[(size_t)dst[e] * HID_DIM + j], v);
    }
}
__global__ void k3_act(const float* __restrict__ h, const float* __restrict__ b1,
                       const float* __restrict__ W2, float* __restrict__ hw) {
    int i = blockIdx.x * blockDim.x + threadIdx.x;
    if (i >= N_NODES) return;
    const float4* h4 = (const float4*)(h + (size_t)i * HID_DIM);
    const float4* b4 = (const float4*)b1;
    const float4* w4 = (const float4*)W2;
    float acc = 0.0f;
#pragma unroll
    for (int q = 0; q < HID_DIM / 4; ++q) {
        float4 hv = h4[q]; float4 bv = b4[q]; float4 wv = w4[q];
        acc += fmaxf(hv.x + bv.x, 0.0f) * wv.x;
        acc += fmaxf(hv.y + bv.y, 0.0f) * wv.y;
        acc += fmaxf(hv.z + bv.z, 0.0f) * wv.z;
        acc += fmaxf(hv.w + bv.w, 0.0f) * wv.w;
    }
    hw[i] = acc;
}
__global__ void k4_spmm2(const int* __restrict__ src, const int* __restrict__ dst,
                         const float* __restrict__ wgt, const float* __restrict__ hw,
                         float* __restrict__ out) {
    int e = blockIdx.x * blockDim.x + threadIdx.x;
    if (e < N_EDGES) atomic_add_f32(&out[dst[e]], wgt[e] * hw[src[e]]);
}

// ---------------------------------------------------------------------------

extern "C" void kernel_launch(void* const* d_in, const int* in_sizes, int n_in,
                              void* d_out, int out_size, void* d_ws, size_t ws_size,
                              hipStream_t stream) {
    const float* x    = (const float*)d_in[0];
    const int*   esrc = (const int*)  d_in[1];
    const int*   edst = (const int*)  d_in[2];
    const float* ew   = (const float*)d_in[3];
    const float* W1   = (const float*)d_in[4];
    const float* b1   = (const float*)d_in[5];
    const float* W2   = (const float*)d_in[6];
    const float* b2   = (const float*)d_in[7];
    float* out = (float*)d_out;
    char* ws = (char*)d_ws;

    // workspace layout
    __half* xwh    = (__half*)ws;                                  // N*16 halfs
    float*  hw     = (float*)(ws + (size_t)N_NODES * HID_DIM * 2); // N floats
    int*    cursor = (int*)(hw + N_NODES);                         // B_BKT ints
    int2*   row    = (int2*)(((size_t)(cursor + B_BKT) + 7) & ~(size_t)7); // N int2
    size_t rec_off = ((size_t)((char*)(row + N_NODES) - ws) + 15) & ~(size_t)15;
    uint2* rec = (uint2*)(ws + rec_off);

    int cap = 0;
    if (ws_size > rec_off) {
        size_t cap_fit = (ws_size - rec_off) / ((size_t)B_BKT * sizeof(uint2));
        cap = (int)(cap_fit < CAP_MAX ? cap_fit : CAP_MAX);
    }

    if (cap >= 4480) {
        z0_init<<<(B_BKT + 255) / 256, 256, 0, stream>>>(cursor, cap);
        g1_xw_mfma<<<(G1_TILES + 3) / 4, 256, 0, stream>>>(x, W1, xwh);
        s1_bin<<<N_EDGES / EPB, 1024, 0, stream>>>(esrc, edst, ew, cursor, rec, cap);
        s2_sort<<<B_BKT, 512, 0, stream>>>(cursor, rec, row, cap);
        p4_layer1<<<N_NODES / 16, 256, 0, stream>>>(row, rec, xwh, b1, W2, hw);
        p5_layer2<<<N_NODES / 32, 256, 0, stream>>>(row, rec, hw, b2, out);
    } else {
        // fallback: atomic scatter
        __half* f_xwh = (__half*)ws;
        float*  f_h   = (float*)(ws + (size_t)N_NODES * HID_DIM * 2);
        float*  f_hw  = f_h + (size_t)N_NODES * HID_DIM;
        int n = N_NODES * HID_DIM;
        f0_zero<<<(n + 255) / 256, 256, 0, stream>>>(f_h, b2, out);
        g1_xw_mfma<<<(G1_TILES + 3) / 4, 256, 0, stream>>>(x, W1, f_xwh);
        k2_spmm1<<<(N_EDGES * 16) / 256, 256, 0, stream>>>(esrc, edst, ew, f_xwh, f_h);
        k3_act<<<(N_NODES + 255) / 256, 256, 0, stream>>>(f_h, b1, W2, f_hw);
        k4_spmm2<<<(N_EDGES + 255) / 256, 256, 0, stream>>>(esrc, edst, ew, f_hw, out);
    }
}

// Round 4
// 418.353 us; speedup vs baseline: 1.7332x; 1.0595x over previous
//
#include <hip/hip_runtime.h>
#include <hip/hip_fp16.h>

#define N_NODES 100000
#define N_EDGES 3200000
#define IN_DIM  512
#define HID_DIM 16

#define B_BKT   782      // ceil(100000 / 128) buckets of 128 nodes
#define BKT_SH  7        // bucket = dst >> 7, dstrel = dst & 127
#define EPB     12500    // edges per s1 block (256 blocks * 12500 = 3.2M)
#define CAP_MAX 4608     // per-bucket record capacity (mean 4093 + ~8 sigma)

#define G1_TILES 6250    // 100000 / 16 rows per MFMA tile (exact)

typedef __attribute__((ext_vector_type(8))) short bf16x8;
typedef __attribute__((ext_vector_type(4))) float f32x4;

__device__ __forceinline__ void atomic_add_f32(float* p, float v) {
    __hip_atomic_fetch_add(p, v, __ATOMIC_RELAXED, __HIP_MEMORY_SCOPE_AGENT);
}
__device__ __forceinline__ int atomic_add_i32(int* p, int v) {
    return __hip_atomic_fetch_add(p, v, __ATOMIC_RELAXED, __HIP_MEMORY_SCOPE_AGENT);
}

__device__ __forceinline__ unsigned short bf16_rne(float f) {
    unsigned u = __float_as_uint(f);
    return (unsigned short)((u + 0x7fffu + ((u >> 16) & 1u)) >> 16);
}

// ---------------------------------------------------------------------------
__global__ void z0_init(int* __restrict__ cursor, int cap) {
    int b = blockIdx.x * blockDim.x + threadIdx.x;
    if (b < B_BKT) cursor[b] = b * cap;
}

// ---------------------------------------------------------------------------
// g1: xw = x @ W1 via MFMA (split-bf16 for fp32-equivalent precision).
// One wave per 16-row tile; x read direct-from-global coalesced; W1 hi/lo
// bf16 fragments staged in LDS (32 KB). D = Ah*Bh + Al*Bh + Ah*Bl.
// Pinned at ~96 us (R0->R1 delta=35 with old=133; R3 prefetch-2 delta=2).
// Left unchanged this round for attribution.
__global__ __launch_bounds__(256) void g1_xw_mfma(const float* __restrict__ x,
                                                  const float* __restrict__ W1,
                                                  __half* __restrict__ xwh) {
    __shared__ alignas(16) unsigned short whi[16 * 64 * 8];
    __shared__ alignas(16) unsigned short wlo[16 * 64 * 8];
    const int t = threadIdx.x;

    for (int idx = t; idx < 16 * 64 * 8; idx += 256) {
        int c  = idx >> 9;
        int l  = (idx >> 3) & 63;
        int tt = idx & 7;
        int k  = c * 32 + ((l >> 4) << 3) + tt;
        int j  = l & 15;
        float w = W1[k * HID_DIM + j];
        unsigned u = __float_as_uint(w);
        float hif = __uint_as_float(u & 0xffff0000u);   // truncated bf16 as f32
        whi[idx] = (unsigned short)(u >> 16);
        wlo[idx] = bf16_rne(w - hif);                   // residual, RNE bf16
    }
    __syncthreads();

    const int lane = t & 63;
    const int wid  = blockIdx.x * 4 + (t >> 6);         // tile id
    if (wid >= G1_TILES) return;
    const int row0 = wid * 16;

    const float* xrow = x + (size_t)(row0 + (lane & 15)) * IN_DIM + ((lane >> 4) << 3);
    const unsigned short* whp = &whi[lane * 8];
    const unsigned short* wlp = &wlo[lane * 8];

    f32x4 acc = {0.f, 0.f, 0.f, 0.f};
    float4 p0[2], p1[2];                                // 2-deep ring buffer
    p0[0] = *(const float4*)(xrow);
    p1[0] = *(const float4*)(xrow + 4);
    p0[1] = *(const float4*)(xrow + 32);
    p1[1] = *(const float4*)(xrow + 36);
#pragma unroll
    for (int c = 0; c < 16; ++c) {
        const int cur = c & 1;                          // static after unroll
        float4 n0, n1;
        if (c < 14) {                                   // prefetch chunk c+2
            n0 = *(const float4*)(xrow + (c + 2) * 32);
            n1 = *(const float4*)(xrow + (c + 2) * 32 + 4);
        }
        float av[8] = {p0[cur].x, p0[cur].y, p0[cur].z, p0[cur].w,
                       p1[cur].x, p1[cur].y, p1[cur].z, p1[cur].w};
        bf16x8 ah, al;
#pragma unroll
        for (int e = 0; e < 8; ++e) {
            unsigned u = __float_as_uint(av[e]);
            ah[e] = (short)(u >> 16);                   // truncated bf16 hi
            float lof = av[e] - __uint_as_float(u & 0xffff0000u);
            al[e] = (short)bf16_rne(lof);               // residual lo
        }
        bf16x8 bh = *(const bf16x8*)(whp + (size_t)c * 512);
        bf16x8 bl = *(const bf16x8*)(wlp + (size_t)c * 512);
        acc = __builtin_amdgcn_mfma_f32_16x16x32_bf16(ah, bh, acc, 0, 0, 0);
        acc = __builtin_amdgcn_mfma_f32_16x16x32_bf16(al, bh, acc, 0, 0, 0);
        acc = __builtin_amdgcn_mfma_f32_16x16x32_bf16(ah, bl, acc, 0, 0, 0);
        if (c < 14) { p0[cur] = n0; p1[cur] = n1; }
    }

    const int n     = lane & 15;
    const int rbase = row0 + ((lane >> 4) << 2);
#pragma unroll
    for (int i = 0; i < 4; ++i)
        xwh[(size_t)(rbase + i) * HID_DIM + n] = __float2half_rn(acc[i]);
}

// ---------------------------------------------------------------------------
// s1: counting-sort edges into coarse bucket regions, block-batched runs.
__global__ __launch_bounds__(1024) void s1_bin(const int* __restrict__ src,
                                               const int* __restrict__ dst,
                                               const float* __restrict__ wgt,
                                               int* __restrict__ cursor,
                                               uint2* __restrict__ rec, int cap) {
    __shared__ int hist[B_BKT];
    __shared__ int base[B_BKT];
    const int t = threadIdx.x;
    for (int b = t; b < B_BKT; b += 1024) hist[b] = 0;
    __syncthreads();
    const int e0 = blockIdx.x * EPB;
    const int4*   d4 = (const int4*)(dst + e0);
    const int4*   s4 = (const int4*)(src + e0);
    const float4* w4 = (const float4*)(wgt + e0);
    const int NG = EPB / 4;
    for (int g = t; g < NG; g += 1024) {
        int4 d = d4[g];
        atomicAdd(&hist[d.x >> BKT_SH], 1);
        atomicAdd(&hist[d.y >> BKT_SH], 1);
        atomicAdd(&hist[d.z >> BKT_SH], 1);
        atomicAdd(&hist[d.w >> BKT_SH], 1);
    }
    __syncthreads();
    for (int b = t; b < B_BKT; b += 1024) {
        int c = hist[b];
        base[b] = c > 0 ? atomic_add_i32(&cursor[b], c) : 0;
    }
    __syncthreads();
    for (int b = t; b < B_BKT; b += 1024) hist[b] = 0;
    __syncthreads();
    for (int g = t; g < NG; g += 1024) {
        int4 d = d4[g];
        int4 s = s4[g];
        float4 w = w4[g];
        {
            int b = d.x >> BKT_SH;
            int pos = base[b] + atomicAdd(&hist[b], 1);
            rec[pos] = make_uint2(((unsigned)s.x << BKT_SH) | (unsigned)(d.x & 127),
                                  __float_as_uint(w.x));
        }
        {
            int b = d.y >> BKT_SH;
            int pos = base[b] + atomicAdd(&hist[b], 1);
            rec[pos] = make_uint2(((unsigned)s.y << BKT_SH) | (unsigned)(d.y & 127),
                                  __float_as_uint(w.y));
        }
        {
            int b = d.z >> BKT_SH;
            int pos = base[b] + atomicAdd(&hist[b], 1);
            rec[pos] = make_uint2(((unsigned)s.z << BKT_SH) | (unsigned)(d.z & 127),
                                  __float_as_uint(w.z));
        }
        {
            int b = d.w >> BKT_SH;
            int pos = base[b] + atomicAdd(&hist[b], 1);
            rec[pos] = make_uint2(((unsigned)s.w << BKT_SH) | (unsigned)(d.w & 127),
                                  __float_as_uint(w.w));
        }
    }
}

// ---------------------------------------------------------------------------
// s2p4: fused per-bucket {counting sort -> sorted LDS} + {layer-1 spmm +
// bias + relu + .W2}. Replaces s2_sort + p4_layer1.
//  A: histogram dstrel (coalesced global read #1)
//  B: scan -> row[] (p5 still consumes row/rec)
//  C: re-read rec (L1/L2-hot) and scatter into SORTED LDS buffer
//  D: sorted LDS -> global rec, fully coalesced (for p5)
//  E: p4-style 16-lane-per-node register accumulation; rec reads are LDS
//     broadcasts (free), only xwh gathers touch memory (L2-resident 3.2MB).
// Eliminates p4's 25.6MB cold rec re-read + scattered global write + row read.
// Accumulation order per node identical to old s2->p4 (bitwise-same hw).
__global__ __launch_bounds__(512) void s2p4(const int* __restrict__ cursor,
                                            uint2* __restrict__ rec,
                                            int2* __restrict__ row,
                                            const __half* __restrict__ xwh,
                                            const float* __restrict__ b1,
                                            const float* __restrict__ W2,
                                            float* __restrict__ hw, int cap) {
    __shared__ uint2 srt[CAP_MAX];
    __shared__ int ocnt[128], scn[128], cur[128];
    const int t = threadIdx.x;
    const int bkt = blockIdx.x;
    const int e0 = bkt * cap;
    int n = cursor[bkt] - e0;
    n = max(0, min(n, cap));
    if (t < 128) ocnt[t] = 0;
    __syncthreads();
    // A: histogram
    for (int i = t; i < n; i += 512)
        atomicAdd(&ocnt[rec[e0 + i].x & 127u], 1);
    __syncthreads();
    // B: exclusive scan + row[]
    if (t < 128) scn[t] = ocnt[t];
    __syncthreads();
    for (int off = 1; off < 128; off <<= 1) {
        int v = 0;
        if (t < 128 && t >= off) v = scn[t - off];
        __syncthreads();
        if (t < 128 && t >= off) scn[t] += v;
        __syncthreads();
    }
    if (t < 128) {
        int b = scn[t] - ocnt[t];          // exclusive prefix
        cur[t] = b;
        int node = (bkt << BKT_SH) + t;
        if (node < N_NODES) row[node] = make_int2(e0 + b, ocnt[t]);
    }
    __syncthreads();
    // C: scatter into sorted LDS (re-read is cache-hot)
    for (int i = t; i < n; i += 512) {
        uint2 r = rec[e0 + i];
        int d = (int)(r.x & 127u);
        int pos = atomicAdd(&cur[d], 1);
        srt[pos] = make_uint2(r.x >> BKT_SH, r.y);   // (src, w)
    }
    __syncthreads();
    // D: coalesced writeback for p5
    for (int i = t; i < n; i += 512) rec[e0 + i] = srt[i];
    // E: layer-1 from sorted LDS, register accumulation (p4 structure)
    const int j = t & 15;
    for (int g = (t >> 4); g < 128; g += 32) {
        const int node = (bkt << BKT_SH) + g;
        if (node >= N_NODES) continue;
        int e = scn[g] - ocnt[g];
        const int end = scn[g];
        float acc = 0.0f;
        for (; e + 4 <= end; e += 4) {
            uint2 q0 = srt[e], q1 = srt[e + 1], q2 = srt[e + 2], q3 = srt[e + 3];
            float f0 = __half2float(xwh[(size_t)q0.x * HID_DIM + j]);
            float f1 = __half2float(xwh[(size_t)q1.x * HID_DIM + j]);
            float f2 = __half2float(xwh[(size_t)q2.x * HID_DIM + j]);
            float f3 = __half2float(xwh[(size_t)q3.x * HID_DIM + j]);
            acc += __uint_as_float(q0.y) * f0;
            acc += __uint_as_float(q1.y) * f1;
            acc += __uint_as_float(q2.y) * f2;
            acc += __uint_as_float(q3.y) * f3;
        }
        for (; e < end; ++e) {
            uint2 q = srt[e];
            acc += __uint_as_float(q.y) * __half2float(xwh[(size_t)q.x * HID_DIM + j]);
        }
        float v = fmaxf(acc + b1[j], 0.0f) * W2[j];
        v += __shfl_xor(v, 1);
        v += __shfl_xor(v, 2);
        v += __shfl_xor(v, 4);
        v += __shfl_xor(v, 8);
        if (j == 0) hw[node] = v;
    }
}

// ---------------------------------------------------------------------------
// p5: spmm2 over the sorted records; 8 lanes/node, coalesced rec reads.
__global__ __launch_bounds__(256) void p5_layer2(const int2* __restrict__ row,
                                                 const uint2* __restrict__ rec,
                                                 const float* __restrict__ hwv,
                                                 const float* __restrict__ b2,
                                                 float* __restrict__ out) {
    const int t = threadIdx.x;
    const int node = blockIdx.x * 32 + (t >> 3);
    const int i = t & 7;
    int2 r = row[node];
    const int end = r.x + r.y;
    int k = r.x + i;
    float s = 0.0f;
    for (; k + 24 < end; k += 32) {
        uint2 a = rec[k], b = rec[k + 8], c = rec[k + 16], d = rec[k + 24];
        float ha = hwv[a.x], hb = hwv[b.x], hc = hwv[c.x], hd = hwv[d.x];
        s += __uint_as_float(a.y) * ha + __uint_as_float(b.y) * hb
           + __uint_as_float(c.y) * hc + __uint_as_float(d.y) * hd;
    }
    for (; k < end; k += 8) {
        uint2 a = rec[k];
        s += __uint_as_float(a.y) * hwv[a.x];
    }
    s += __shfl_xor(s, 1);
    s += __shfl_xor(s, 2);
    s += __shfl_xor(s, 4);
    if (i == 0) out[node] = b2[0] + s;
}

// ---------------------------------------------------------------------------
// fallback path (atomic scatter) if workspace is too small
// ---------------------------------------------------------------------------
__global__ void f0_zero(float* __restrict__ h, const float* __restrict__ b2,
                        float* __restrict__ out) {
    int i = blockIdx.x * blockDim.x + threadIdx.x;
    if (i < N_NODES * HID_DIM) h[i] = 0.0f;
    if (i < N_NODES) out[i] = b2[0];
}
__global__ void k2_spmm1(const int* __restrict__ src, const int* __restrict__ dst,
                         const float* __restrict__ wgt, const __half* __restrict__ xwh,
                         float* __restrict__ h) {
    int t = blockIdx.x * blockDim.x + threadIdx.x;
    int e = t >> 4;
    int j = t & (HID_DIM - 1);
    if (e < N_EDGES) {
        float v = wgt[e] * __half2float(xwh[(size_t)src[e] * HID_DIM + j]);
        atomic_add_f32(&h[(size_t)dst[e] * HID_DIM + j], v);
    }
}
__global__ void k3_act(const float* __restrict__ h, const float* __restrict__ b1,
                       const float* __restrict__ W2, float* __restrict__ hw) {
    int i = blockIdx.x * blockDim.x + threadIdx.x;
    if (i >= N_NODES) return;
    const float4* h4 = (const float4*)(h + (size_t)i * HID_DIM);
    const float4* b4 = (const float4*)b1;
    const float4* w4 = (const float4*)W2;
    float acc = 0.0f;
#pragma unroll
    for (int q = 0; q < HID_DIM / 4; ++q) {
        float4 hv = h4[q]; float4 bv = b4[q]; float4 wv = w4[q];
        acc += fmaxf(hv.x + bv.x, 0.0f) * wv.x;
        acc += fmaxf(hv.y + bv.y, 0.0f) * wv.y;
        acc += fmaxf(hv.z + bv.z, 0.0f) * wv.z;
        acc += fmaxf(hv.w + bv.w, 0.0f) * wv.w;
    }
    hw[i] = acc;
}
__global__ void k4_spmm2(const int* __restrict__ src, const int* __restrict__ dst,
                         const float* __restrict__ wgt, const float* __restrict__ hw,
                         float* __restrict__ out) {
    int e = blockIdx.x * blockDim.x + threadIdx.x;
    if (e < N_EDGES) atomic_add_f32(&out[dst[e]], wgt[e] * hw[src[e]]);
}

// ---------------------------------------------------------------------------

extern "C" void kernel_launch(void* const* d_in, const int* in_sizes, int n_in,
                              void* d_out, int out_size, void* d_ws, size_t ws_size,
                              hipStream_t stream) {
    const float* x    = (const float*)d_in[0];
    const int*   esrc = (const int*)  d_in[1];
    const int*   edst = (const int*)  d_in[2];
    const float* ew   = (const float*)d_in[3];
    const float* W1   = (const float*)d_in[4];
    const float* b1   = (const float*)d_in[5];
    const float* W2   = (const float*)d_in[6];
    const float* b2   = (const float*)d_in[7];
    float* out = (float*)d_out;
    char* ws = (char*)d_ws;

    // workspace layout
    __half* xwh    = (__half*)ws;                                  // N*16 halfs
    float*  hw     = (float*)(ws + (size_t)N_NODES * HID_DIM * 2); // N floats
    int*    cursor = (int*)(hw + N_NODES);                         // B_BKT ints
    int2*   row    = (int2*)(((size_t)(cursor + B_BKT) + 7) & ~(size_t)7); // N int2
    size_t rec_off = ((size_t)((char*)(row + N_NODES) - ws) + 15) & ~(size_t)15;
    uint2* rec = (uint2*)(ws + rec_off);

    int cap = 0;
    if (ws_size > rec_off) {
        size_t cap_fit = (ws_size - rec_off) / ((size_t)B_BKT * sizeof(uint2));
        cap = (int)(cap_fit < CAP_MAX ? cap_fit : CAP_MAX);
    }

    if (cap >= 4480) {
        z0_init<<<(B_BKT + 255) / 256, 256, 0, stream>>>(cursor, cap);
        g1_xw_mfma<<<(G1_TILES + 3) / 4, 256, 0, stream>>>(x, W1, xwh);
        s1_bin<<<N_EDGES / EPB, 1024, 0, stream>>>(esrc, edst, ew, cursor, rec, cap);
        s2p4<<<B_BKT, 512, 0, stream>>>(cursor, rec, row, xwh, b1, W2, hw, cap);
        p5_layer2<<<N_NODES / 32, 256, 0, stream>>>(row, rec, hw, b2, out);
    } else {
        // fallback: atomic scatter
        __half* f_xwh = (__half*)ws;
        float*  f_h   = (float*)(ws + (size_t)N_NODES * HID_DIM * 2);
        float*  f_hw  = f_h + (size_t)N_NODES * HID_DIM;
        int n = N_NODES * HID_DIM;
        f0_zero<<<(n + 255) / 256, 256, 0, stream>>>(f_h, b2, out);
        g1_xw_mfma<<<(G1_TILES + 3) / 4, 256, 0, stream>>>(x, W1, f_xwh);
        k2_spmm1<<<(N_EDGES * 16) / 256, 256, 0, stream>>>(esrc, edst, ew, f_xwh, f_h);
        k3_act<<<(N_NODES + 255) / 256, 256, 0, stream>>>(f_h, b1, W2, f_hw);
        k4_spmm2<<<(N_EDGES + 255) / 256, 256, 0, stream>>>(esrc, edst, ew, f_hw, out);
    }
}

// Round 5
// 406.596 us; speedup vs baseline: 1.7834x; 1.0289x over previous
//
#include <hip/hip_runtime.h>
#include <hip/hip_fp16.h>

#define N_NODES 100000
#define N_EDGES 3200000
#define IN_DIM  512
#define HID_DIM 16

#define B_BKT   782      // ceil(100000 / 128) buckets of 128 nodes
#define BKT_SH  7        // bucket = dst >> 7, dstrel = dst & 127
#define EPB2    5000     // edges per s1 block (640 blocks * 5000 = 3.2M)
#define NBLK2   640
#define CAP_MAX 4608     // per-bucket record capacity (mean 4093 + ~8 sigma)

#define G1_TILES 6250    // 100000 / 16 rows per MFMA tile (exact)

typedef __attribute__((ext_vector_type(8))) short bf16x8;
typedef __attribute__((ext_vector_type(4))) float f32x4;

__device__ __forceinline__ void atomic_add_f32(float* p, float v) {
    __hip_atomic_fetch_add(p, v, __ATOMIC_RELAXED, __HIP_MEMORY_SCOPE_AGENT);
}
__device__ __forceinline__ int atomic_add_i32(int* p, int v) {
    return __hip_atomic_fetch_add(p, v, __ATOMIC_RELAXED, __HIP_MEMORY_SCOPE_AGENT);
}

__device__ __forceinline__ unsigned short bf16_rne(float f) {
    unsigned u = __float_as_uint(f);
    return (unsigned short)((u + 0x7fffu + ((u >> 16) & 1u)) >> 16);
}

// ---------------------------------------------------------------------------
__global__ void z0_init(int* __restrict__ cursor, int cap) {
    int b = blockIdx.x * blockDim.x + threadIdx.x;
    if (b < B_BKT) cursor[b] = b * cap;
}

// ---------------------------------------------------------------------------
// g1: xw = x @ W1 via MFMA (split-bf16 for fp32-equivalent precision).
// Pinned at ~96 us; unchanged for attribution.
__global__ __launch_bounds__(256) void g1_xw_mfma(const float* __restrict__ x,
                                                  const float* __restrict__ W1,
                                                  __half* __restrict__ xwh) {
    __shared__ alignas(16) unsigned short whi[16 * 64 * 8];
    __shared__ alignas(16) unsigned short wlo[16 * 64 * 8];
    const int t = threadIdx.x;

    for (int idx = t; idx < 16 * 64 * 8; idx += 256) {
        int c  = idx >> 9;
        int l  = (idx >> 3) & 63;
        int tt = idx & 7;
        int k  = c * 32 + ((l >> 4) << 3) + tt;
        int j  = l & 15;
        float w = W1[k * HID_DIM + j];
        unsigned u = __float_as_uint(w);
        float hif = __uint_as_float(u & 0xffff0000u);   // truncated bf16 as f32
        whi[idx] = (unsigned short)(u >> 16);
        wlo[idx] = bf16_rne(w - hif);                   // residual, RNE bf16
    }
    __syncthreads();

    const int lane = t & 63;
    const int wid  = blockIdx.x * 4 + (t >> 6);         // tile id
    if (wid >= G1_TILES) return;
    const int row0 = wid * 16;

    const float* xrow = x + (size_t)(row0 + (lane & 15)) * IN_DIM + ((lane >> 4) << 3);
    const unsigned short* whp = &whi[lane * 8];
    const unsigned short* wlp = &wlo[lane * 8];

    f32x4 acc = {0.f, 0.f, 0.f, 0.f};
    float4 p0[2], p1[2];                                // 2-deep ring buffer
    p0[0] = *(const float4*)(xrow);
    p1[0] = *(const float4*)(xrow + 4);
    p0[1] = *(const float4*)(xrow + 32);
    p1[1] = *(const float4*)(xrow + 36);
#pragma unroll
    for (int c = 0; c < 16; ++c) {
        const int cur = c & 1;                          // static after unroll
        float4 n0, n1;
        if (c < 14) {                                   // prefetch chunk c+2
            n0 = *(const float4*)(xrow + (c + 2) * 32);
            n1 = *(const float4*)(xrow + (c + 2) * 32 + 4);
        }
        float av[8] = {p0[cur].x, p0[cur].y, p0[cur].z, p0[cur].w,
                       p1[cur].x, p1[cur].y, p1[cur].z, p1[cur].w};
        bf16x8 ah, al;
#pragma unroll
        for (int e = 0; e < 8; ++e) {
            unsigned u = __float_as_uint(av[e]);
            ah[e] = (short)(u >> 16);                   // truncated bf16 hi
            float lof = av[e] - __uint_as_float(u & 0xffff0000u);
            al[e] = (short)bf16_rne(lof);               // residual lo
        }
        bf16x8 bh = *(const bf16x8*)(whp + (size_t)c * 512);
        bf16x8 bl = *(const bf16x8*)(wlp + (size_t)c * 512);
        acc = __builtin_amdgcn_mfma_f32_16x16x32_bf16(ah, bh, acc, 0, 0, 0);
        acc = __builtin_amdgcn_mfma_f32_16x16x32_bf16(al, bh, acc, 0, 0, 0);
        acc = __builtin_amdgcn_mfma_f32_16x16x32_bf16(ah, bl, acc, 0, 0, 0);
        if (c < 14) { p0[cur] = n0; p1[cur] = n1; }
    }

    const int n     = lane & 15;
    const int rbase = row0 + ((lane >> 4) << 2);
#pragma unroll
    for (int i = 0; i < 4; ++i)
        xwh[(size_t)(rbase + i) * HID_DIM + n] = __float2half_rn(acc[i]);
}

// ---------------------------------------------------------------------------
// s1_bin2: bucket binning with RUN-COALESCED global writes.
// Old s1 wrote 25.6MB as isolated 8B records scattered over 28.8MB with
// cross-XCD partial-line sharing (~4-8x HBM write amplification). Here each
// block counting-sorts its 5000 edges in LDS first, then writes each
// bucket's records as a contiguous run (avg 6.4 recs) to its atomically
// reserved global range -> ~6x fewer write segments, runs are XCD-private.
//  1: LDS histogram of dst-buckets
//  2: 512-wide scan (thread t owns buckets 2t,2t+1) -> local bases;
//     one cursor atomic per nonzero bucket -> global bases
//  3: re-read edges (L2-hot), scatter into sorted LDS (srt + bkt-id)
//  4: writeback in sorted order: rec[gbase[b] + i - lbase[b]] = srt[i]
// LDS 61.4KB -> 2 blocks/CU.
__global__ __launch_bounds__(512) void s1_bin2(const int* __restrict__ src,
                                               const int* __restrict__ dst,
                                               const float* __restrict__ wgt,
                                               int* __restrict__ cursor,
                                               uint2* __restrict__ rec, int cap) {
    __shared__ uint2 srt[EPB2];                  // 40000 B
    __shared__ unsigned short bkt[EPB2];         // 10000 B
    __shared__ int hist[B_BKT];                  //  3128 B (later: local cursor)
    __shared__ int lbase[B_BKT];                 //  3128 B
    __shared__ int gbase[B_BKT];                 //  3128 B
    __shared__ int scn[512];                     //  2048 B
    const int t = threadIdx.x;
    for (int b = t; b < B_BKT; b += 512) hist[b] = 0;
    __syncthreads();

    const int e0 = blockIdx.x * EPB2;
    const int4*   d4 = (const int4*)(dst + e0);
    const int4*   s4 = (const int4*)(src + e0);
    const float4* w4 = (const float4*)(wgt + e0);
    const int NG = EPB2 / 4;

    // 1: histogram
    for (int g = t; g < NG; g += 512) {
        int4 d = d4[g];
        atomicAdd(&hist[d.x >> BKT_SH], 1);
        atomicAdd(&hist[d.y >> BKT_SH], 1);
        atomicAdd(&hist[d.z >> BKT_SH], 1);
        atomicAdd(&hist[d.w >> BKT_SH], 1);
    }
    __syncthreads();

    // 2a: local exclusive scan over 782 buckets (pairs per thread)
    int c0 = 0, c1 = 0;
    if (t < 391) { c0 = hist[2 * t]; c1 = hist[2 * t + 1]; }
    int s = c0 + c1;
    scn[t] = s;
    __syncthreads();
    for (int off = 1; off < 512; off <<= 1) {
        int v = (t >= off) ? scn[t - off] : 0;
        __syncthreads();
        scn[t] += v;
        __syncthreads();
    }
    int excl = scn[t] - s;
    if (t < 391) {
        lbase[2 * t]     = excl;
        lbase[2 * t + 1] = excl + c0;
    }
    __syncthreads();

    // 2b: reserve global ranges; turn hist into a running local cursor
    for (int b = t; b < B_BKT; b += 512) {
        int c = hist[b];
        gbase[b] = c > 0 ? atomic_add_i32(&cursor[b], c) : 0;
    }
    __syncthreads();
    for (int b = t; b < B_BKT; b += 512) hist[b] = lbase[b];
    __syncthreads();

    // 3: scatter into sorted LDS (edge re-read is L2-hot)
    for (int g = t; g < NG; g += 512) {
        int4 d = d4[g];
        int4 sv = s4[g];
        float4 w = w4[g];
        {
            int b = d.x >> BKT_SH;
            int pos = atomicAdd(&hist[b], 1);
            srt[pos] = make_uint2(((unsigned)sv.x << BKT_SH) | (unsigned)(d.x & 127),
                                  __float_as_uint(w.x));
            bkt[pos] = (unsigned short)b;
        }
        {
            int b = d.y >> BKT_SH;
            int pos = atomicAdd(&hist[b], 1);
            srt[pos] = make_uint2(((unsigned)sv.y << BKT_SH) | (unsigned)(d.y & 127),
                                  __float_as_uint(w.y));
            bkt[pos] = (unsigned short)b;
        }
        {
            int b = d.z >> BKT_SH;
            int pos = atomicAdd(&hist[b], 1);
            srt[pos] = make_uint2(((unsigned)sv.z << BKT_SH) | (unsigned)(d.z & 127),
                                  __float_as_uint(w.z));
            bkt[pos] = (unsigned short)b;
        }
        {
            int b = d.w >> BKT_SH;
            int pos = atomicAdd(&hist[b], 1);
            srt[pos] = make_uint2(((unsigned)sv.w << BKT_SH) | (unsigned)(d.w & 127),
                                  __float_as_uint(w.w));
            bkt[pos] = (unsigned short)b;
        }
    }
    __syncthreads();

    // 4: run-coalesced writeback
    for (int i = t; i < EPB2; i += 512) {
        int b = bkt[i];
        rec[gbase[b] + (i - lbase[b])] = srt[i];
    }
}

// ---------------------------------------------------------------------------
// s2p4: fused per-bucket {counting sort -> sorted LDS} + {layer-1 spmm +
// bias + relu + .W2}. (unchanged from R4)
__global__ __launch_bounds__(512) void s2p4(const int* __restrict__ cursor,
                                            uint2* __restrict__ rec,
                                            int2* __restrict__ row,
                                            const __half* __restrict__ xwh,
                                            const float* __restrict__ b1,
                                            const float* __restrict__ W2,
                                            float* __restrict__ hw, int cap) {
    __shared__ uint2 srt[CAP_MAX];
    __shared__ int ocnt[128], scn[128], cur[128];
    const int t = threadIdx.x;
    const int bkt = blockIdx.x;
    const int e0 = bkt * cap;
    int n = cursor[bkt] - e0;
    n = max(0, min(n, cap));
    if (t < 128) ocnt[t] = 0;
    __syncthreads();
    // A: histogram
    for (int i = t; i < n; i += 512)
        atomicAdd(&ocnt[rec[e0 + i].x & 127u], 1);
    __syncthreads();
    // B: exclusive scan + row[]
    if (t < 128) scn[t] = ocnt[t];
    __syncthreads();
    for (int off = 1; off < 128; off <<= 1) {
        int v = 0;
        if (t < 128 && t >= off) v = scn[t - off];
        __syncthreads();
        if (t < 128 && t >= off) scn[t] += v;
        __syncthreads();
    }
    if (t < 128) {
        int b = scn[t] - ocnt[t];          // exclusive prefix
        cur[t] = b;
        int node = (bkt << BKT_SH) + t;
        if (node < N_NODES) row[node] = make_int2(e0 + b, ocnt[t]);
    }
    __syncthreads();
    // C: scatter into sorted LDS (re-read is cache-hot)
    for (int i = t; i < n; i += 512) {
        uint2 r = rec[e0 + i];
        int d = (int)(r.x & 127u);
        int pos = atomicAdd(&cur[d], 1);
        srt[pos] = make_uint2(r.x >> BKT_SH, r.y);   // (src, w)
    }
    __syncthreads();
    // D: coalesced writeback for p5
    for (int i = t; i < n; i += 512) rec[e0 + i] = srt[i];
    // E: layer-1 from sorted LDS, register accumulation
    const int j = t & 15;
    for (int g = (t >> 4); g < 128; g += 32) {
        const int node = (bkt << BKT_SH) + g;
        if (node >= N_NODES) continue;
        int e = scn[g] - ocnt[g];
        const int end = scn[g];
        float acc = 0.0f;
        for (; e + 4 <= end; e += 4) {
            uint2 q0 = srt[e], q1 = srt[e + 1], q2 = srt[e + 2], q3 = srt[e + 3];
            float f0 = __half2float(xwh[(size_t)q0.x * HID_DIM + j]);
            float f1 = __half2float(xwh[(size_t)q1.x * HID_DIM + j]);
            float f2 = __half2float(xwh[(size_t)q2.x * HID_DIM + j]);
            float f3 = __half2float(xwh[(size_t)q3.x * HID_DIM + j]);
            acc += __uint_as_float(q0.y) * f0;
            acc += __uint_as_float(q1.y) * f1;
            acc += __uint_as_float(q2.y) * f2;
            acc += __uint_as_float(q3.y) * f3;
        }
        for (; e < end; ++e) {
            uint2 q = srt[e];
            acc += __uint_as_float(q.y) * __half2float(xwh[(size_t)q.x * HID_DIM + j]);
        }
        float v = fmaxf(acc + b1[j], 0.0f) * W2[j];
        v += __shfl_xor(v, 1);
        v += __shfl_xor(v, 2);
        v += __shfl_xor(v, 4);
        v += __shfl_xor(v, 8);
        if (j == 0) hw[node] = v;
    }
}

// ---------------------------------------------------------------------------
// p5: spmm2 over the sorted records; 8 lanes/node, coalesced rec reads.
__global__ __launch_bounds__(256) void p5_layer2(const int2* __restrict__ row,
                                                 const uint2* __restrict__ rec,
                                                 const float* __restrict__ hwv,
                                                 const float* __restrict__ b2,
                                                 float* __restrict__ out) {
    const int t = threadIdx.x;
    const int node = blockIdx.x * 32 + (t >> 3);
    const int i = t & 7;
    int2 r = row[node];
    const int end = r.x + r.y;
    int k = r.x + i;
    float s = 0.0f;
    for (; k + 24 < end; k += 32) {
        uint2 a = rec[k], b = rec[k + 8], c = rec[k + 16], d = rec[k + 24];
        float ha = hwv[a.x], hb = hwv[b.x], hc = hwv[c.x], hd = hwv[d.x];
        s += __uint_as_float(a.y) * ha + __uint_as_float(b.y) * hb
           + __uint_as_float(c.y) * hc + __uint_as_float(d.y) * hd;
    }
    for (; k < end; k += 8) {
        uint2 a = rec[k];
        s += __uint_as_float(a.y) * hwv[a.x];
    }
    s += __shfl_xor(s, 1);
    s += __shfl_xor(s, 2);
    s += __shfl_xor(s, 4);
    if (i == 0) out[node] = b2[0] + s;
}

// ---------------------------------------------------------------------------
// fallback path (atomic scatter) if workspace is too small
// ---------------------------------------------------------------------------
__global__ void f0_zero(float* __restrict__ h, const float* __restrict__ b2,
                        float* __restrict__ out) {
    int i = blockIdx.x * blockDim.x + threadIdx.x;
    if (i < N_NODES * HID_DIM) h[i] = 0.0f;
    if (i < N_NODES) out[i] = b2[0];
}
__global__ void k2_spmm1(const int* __restrict__ src, const int* __restrict__ dst,
                         const float* __restrict__ wgt, const __half* __restrict__ xwh,
                         float* __restrict__ h) {
    int t = blockIdx.x * blockDim.x + threadIdx.x;
    int e = t >> 4;
    int j = t & (HID_DIM - 1);
    if (e < N_EDGES) {
        float v = wgt[e] * __half2float(xwh[(size_t)src[e] * HID_DIM + j]);
        atomic_add_f32(&h[(size_t)dst[e] * HID_DIM + j], v);
    }
}
__global__ void k3_act(const float* __restrict__ h, const float* __restrict__ b1,
                       const float* __restrict__ W2, float* __restrict__ hw) {
    int i = blockIdx.x * blockDim.x + threadIdx.x;
    if (i >= N_NODES) return;
    const float4* h4 = (const float4*)(h + (size_t)i * HID_DIM);
    const float4* b4 = (const float4*)b1;
    const float4* w4 = (const float4*)W2;
    float acc = 0.0f;
#pragma unroll
    for (int q = 0; q < HID_DIM / 4; ++q) {
        float4 hv = h4[q]; float4 bv = b4[q]; float4 wv = w4[q];
        acc += fmaxf(hv.x + bv.x, 0.0f) * wv.x;
        acc += fmaxf(hv.y + bv.y, 0.0f) * wv.y;
        acc += fmaxf(hv.z + bv.z, 0.0f) * wv.z;
        acc += fmaxf(hv.w + bv.w, 0.0f) * wv.w;
    }
    hw[i] = acc;
}
__global__ void k4_spmm2(const int* __restrict__ src, const int* __restrict__ dst,
                         const float* __restrict__ wgt, const float* __restrict__ hw,
                         float* __restrict__ out) {
    int e = blockIdx.x * blockDim.x + threadIdx.x;
    if (e < N_EDGES) atomic_add_f32(&out[dst[e]], wgt[e] * hw[src[e]]);
}

// ---------------------------------------------------------------------------

extern "C" void kernel_launch(void* const* d_in, const int* in_sizes, int n_in,
                              void* d_out, int out_size, void* d_ws, size_t ws_size,
                              hipStream_t stream) {
    const float* x    = (const float*)d_in[0];
    const int*   esrc = (const int*)  d_in[1];
    const int*   edst = (const int*)  d_in[2];
    const float* ew   = (const float*)d_in[3];
    const float* W1   = (const float*)d_in[4];
    const float* b1   = (const float*)d_in[5];
    const float* W2   = (const float*)d_in[6];
    const float* b2   = (const float*)d_in[7];
    float* out = (float*)d_out;
    char* ws = (char*)d_ws;

    // workspace layout
    __half* xwh    = (__half*)ws;                                  // N*16 halfs
    float*  hw     = (float*)(ws + (size_t)N_NODES * HID_DIM * 2); // N floats
    int*    cursor = (int*)(hw + N_NODES);                         // B_BKT ints
    int2*   row    = (int2*)(((size_t)(cursor + B_BKT) + 7) & ~(size_t)7); // N int2
    size_t rec_off = ((size_t)((char*)(row + N_NODES) - ws) + 15) & ~(size_t)15;
    uint2* rec = (uint2*)(ws + rec_off);

    int cap = 0;
    if (ws_size > rec_off) {
        size_t cap_fit = (ws_size - rec_off) / ((size_t)B_BKT * sizeof(uint2));
        cap = (int)(cap_fit < CAP_MAX ? cap_fit : CAP_MAX);
    }

    if (cap >= 4480) {
        z0_init<<<(B_BKT + 255) / 256, 256, 0, stream>>>(cursor, cap);
        g1_xw_mfma<<<(G1_TILES + 3) / 4, 256, 0, stream>>>(x, W1, xwh);
        s1_bin2<<<NBLK2, 512, 0, stream>>>(esrc, edst, ew, cursor, rec, cap);
        s2p4<<<B_BKT, 512, 0, stream>>>(cursor, rec, row, xwh, b1, W2, hw, cap);
        p5_layer2<<<N_NODES / 32, 256, 0, stream>>>(row, rec, hw, b2, out);
    } else {
        // fallback: atomic scatter
        __half* f_xwh = (__half*)ws;
        float*  f_h   = (float*)(ws + (size_t)N_NODES * HID_DIM * 2);
        float*  f_hw  = f_h + (size_t)N_NODES * HID_DIM;
        int n = N_NODES * HID_DIM;
        f0_zero<<<(n + 255) / 256, 256, 0, stream>>>(f_h, b2, out);
        g1_xw_mfma<<<(G1_TILES + 3) / 4, 256, 0, stream>>>(x, W1, f_xwh);
        k2_spmm1<<<(N_EDGES * 16) / 256, 256, 0, stream>>>(esrc, edst, ew, f_xwh, f_h);
        k3_act<<<(N_NODES + 255) / 256, 256, 0, stream>>>(f_h, b1, W2, f_hw);
        k4_spmm2<<<(N_EDGES + 255) / 256, 256, 0, stream>>>(esrc, edst, ew, f_hw, out);
    }
}

// Round 6
// 392.919 us; speedup vs baseline: 1.8454x; 1.0348x over previous
//
#include <hip/hip_runtime.h>
#include <hip/hip_fp16.h>

#define N_NODES 100000
#define N_EDGES 3200000
#define IN_DIM  512
#define HID_DIM 16

#define B_BKT   782      // ceil(100000 / 128) buckets of 128 nodes
#define BKT_SH  7        // bucket = dst >> 7, dstrel = dst & 127
#define EPB2    5000     // edges per s1 block (640 blocks * 5000 = 3.2M)
#define NBLK2   640
#define CAP_MAX 4608     // per-bucket record capacity (mean 4093 + ~8 sigma)

#define G1_TILES 6250    // 100000 / 16 rows per MFMA tile (exact)
#define G1_BLK   782     // ceil(6250 / 8) tiles, 8 waves (512 thr) per block
#define MERGED_SMEM 61440

typedef __attribute__((ext_vector_type(8))) short bf16x8;
typedef __attribute__((ext_vector_type(4))) float f32x4;

__device__ __forceinline__ void atomic_add_f32(float* p, float v) {
    __hip_atomic_fetch_add(p, v, __ATOMIC_RELAXED, __HIP_MEMORY_SCOPE_AGENT);
}
__device__ __forceinline__ int atomic_add_i32(int* p, int v) {
    return __hip_atomic_fetch_add(p, v, __ATOMIC_RELAXED, __HIP_MEMORY_SCOPE_AGENT);
}

__device__ __forceinline__ unsigned short bf16_rne(float f) {
    unsigned u = __float_as_uint(f);
    return (unsigned short)((u + 0x7fffu + ((u >> 16) & 1u)) >> 16);
}

// ---------------------------------------------------------------------------
__global__ void z0_init(int* __restrict__ cursor, int cap) {
    int b = blockIdx.x * blockDim.x + threadIdx.x;
    if (b < B_BKT) cursor[b] = b * cap;
}

// ---------------------------------------------------------------------------
// m1_gs: MERGED g1 (x@W1 MFMA) + s1 (edge bucket binning) in one launch.
// The two are data-independent; both are latency-bound (<35% of any pipe),
// so co-residency fills each other's stall slots. Blocks [0,NBLK2) run the
// s1_bin2 body (512 thr); blocks [NBLK2, NBLK2+G1_BLK) run the g1 body at
// 8 waves = 8 tiles per block. LDS is unioned via dynamic shared memory
// (61.4 KB = max(s1 61.4, g1 32)) -> 2 blocks/CU. Algorithms are unchanged
// instruction-for-instruction vs R5.
__global__ __launch_bounds__(512) void m1_gs(const float* __restrict__ x,
                                             const float* __restrict__ W1,
                                             __half* __restrict__ xwh,
                                             const int* __restrict__ src,
                                             const int* __restrict__ dst,
                                             const float* __restrict__ wgt,
                                             int* __restrict__ cursor,
                                             uint2* __restrict__ rec, int cap) {
    extern __shared__ __align__(16) char smem[];
    const int t = threadIdx.x;

    if (blockIdx.x < NBLK2) {
        // ---------------- s1_bin2 body ----------------
        uint2*          srt   = (uint2*)smem;                        // 40000 B
        unsigned short* bkt   = (unsigned short*)(smem + 40000);     // 10000 B
        int*            hist  = (int*)(smem + 50000);                //  3128 B
        int*            lbase = (int*)(smem + 53128);                //  3128 B
        int*            gbase = (int*)(smem + 56256);                //  3128 B
        int*            scn   = (int*)(smem + 59384);                //  2048 B

        for (int b = t; b < B_BKT; b += 512) hist[b] = 0;
        __syncthreads();

        const int e0 = blockIdx.x * EPB2;
        const int4*   d4 = (const int4*)(dst + e0);
        const int4*   s4 = (const int4*)(src + e0);
        const float4* w4 = (const float4*)(wgt + e0);
        const int NG = EPB2 / 4;

        // 1: histogram
        for (int g = t; g < NG; g += 512) {
            int4 d = d4[g];
            atomicAdd(&hist[d.x >> BKT_SH], 1);
            atomicAdd(&hist[d.y >> BKT_SH], 1);
            atomicAdd(&hist[d.z >> BKT_SH], 1);
            atomicAdd(&hist[d.w >> BKT_SH], 1);
        }
        __syncthreads();

        // 2a: local exclusive scan over 782 buckets (pairs per thread)
        int c0 = 0, c1 = 0;
        if (t < 391) { c0 = hist[2 * t]; c1 = hist[2 * t + 1]; }
        int s = c0 + c1;
        scn[t] = s;
        __syncthreads();
        for (int off = 1; off < 512; off <<= 1) {
            int v = (t >= off) ? scn[t - off] : 0;
            __syncthreads();
            scn[t] += v;
            __syncthreads();
        }
        int excl = scn[t] - s;
        if (t < 391) {
            lbase[2 * t]     = excl;
            lbase[2 * t + 1] = excl + c0;
        }
        __syncthreads();

        // 2b: reserve global ranges; turn hist into a running local cursor
        for (int b = t; b < B_BKT; b += 512) {
            int c = hist[b];
            gbase[b] = c > 0 ? atomic_add_i32(&cursor[b], c) : 0;
        }
        __syncthreads();
        for (int b = t; b < B_BKT; b += 512) hist[b] = lbase[b];
        __syncthreads();

        // 3: scatter into sorted LDS (edge re-read is L2-hot)
        for (int g = t; g < NG; g += 512) {
            int4 d = d4[g];
            int4 sv = s4[g];
            float4 w = w4[g];
            {
                int b = d.x >> BKT_SH;
                int pos = atomicAdd(&hist[b], 1);
                srt[pos] = make_uint2(((unsigned)sv.x << BKT_SH) | (unsigned)(d.x & 127),
                                      __float_as_uint(w.x));
                bkt[pos] = (unsigned short)b;
            }
            {
                int b = d.y >> BKT_SH;
                int pos = atomicAdd(&hist[b], 1);
                srt[pos] = make_uint2(((unsigned)sv.y << BKT_SH) | (unsigned)(d.y & 127),
                                      __float_as_uint(w.y));
                bkt[pos] = (unsigned short)b;
            }
            {
                int b = d.z >> BKT_SH;
                int pos = atomicAdd(&hist[b], 1);
                srt[pos] = make_uint2(((unsigned)sv.z << BKT_SH) | (unsigned)(d.z & 127),
                                      __float_as_uint(w.z));
                bkt[pos] = (unsigned short)b;
            }
            {
                int b = d.w >> BKT_SH;
                int pos = atomicAdd(&hist[b], 1);
                srt[pos] = make_uint2(((unsigned)sv.w << BKT_SH) | (unsigned)(d.w & 127),
                                      __float_as_uint(w.w));
                bkt[pos] = (unsigned short)b;
            }
        }
        __syncthreads();

        // 4: run-coalesced writeback
        for (int i = t; i < EPB2; i += 512) {
            int b = bkt[i];
            rec[gbase[b] + (i - lbase[b])] = srt[i];
        }
    } else {
        // ---------------- g1 body (8 waves = 8 tiles per block) ----------------
        unsigned short* whi = (unsigned short*)smem;              // 16384 B
        unsigned short* wlo = (unsigned short*)(smem + 16384);    // 16384 B

        for (int idx = t; idx < 16 * 64 * 8; idx += 512) {
            int c  = idx >> 9;
            int l  = (idx >> 3) & 63;
            int tt = idx & 7;
            int k  = c * 32 + ((l >> 4) << 3) + tt;
            int j  = l & 15;
            float w = W1[k * HID_DIM + j];
            unsigned u = __float_as_uint(w);
            float hif = __uint_as_float(u & 0xffff0000u);   // truncated bf16 as f32
            whi[idx] = (unsigned short)(u >> 16);
            wlo[idx] = bf16_rne(w - hif);                   // residual, RNE bf16
        }
        __syncthreads();

        const int lane = t & 63;
        const int wid  = (blockIdx.x - NBLK2) * 8 + (t >> 6);   // tile id
        if (wid >= G1_TILES) return;
        const int row0 = wid * 16;

        const float* xrow = x + (size_t)(row0 + (lane & 15)) * IN_DIM + ((lane >> 4) << 3);
        const unsigned short* whp = &whi[lane * 8];
        const unsigned short* wlp = &wlo[lane * 8];

        f32x4 acc = {0.f, 0.f, 0.f, 0.f};
        float4 p0[2], p1[2];                                // 2-deep ring buffer
        p0[0] = *(const float4*)(xrow);
        p1[0] = *(const float4*)(xrow + 4);
        p0[1] = *(const float4*)(xrow + 32);
        p1[1] = *(const float4*)(xrow + 36);
#pragma unroll
        for (int c = 0; c < 16; ++c) {
            const int cur = c & 1;                          // static after unroll
            float4 n0, n1;
            if (c < 14) {                                   // prefetch chunk c+2
                n0 = *(const float4*)(xrow + (c + 2) * 32);
                n1 = *(const float4*)(xrow + (c + 2) * 32 + 4);
            }
            float av[8] = {p0[cur].x, p0[cur].y, p0[cur].z, p0[cur].w,
                           p1[cur].x, p1[cur].y, p1[cur].z, p1[cur].w};
            bf16x8 ah, al;
#pragma unroll
            for (int e = 0; e < 8; ++e) {
                unsigned u = __float_as_uint(av[e]);
                ah[e] = (short)(u >> 16);                   // truncated bf16 hi
                float lof = av[e] - __uint_as_float(u & 0xffff0000u);
                al[e] = (short)bf16_rne(lof);               // residual lo
            }
            bf16x8 bh = *(const bf16x8*)(whp + (size_t)c * 512);
            bf16x8 bl = *(const bf16x8*)(wlp + (size_t)c * 512);
            acc = __builtin_amdgcn_mfma_f32_16x16x32_bf16(ah, bh, acc, 0, 0, 0);
            acc = __builtin_amdgcn_mfma_f32_16x16x32_bf16(al, bh, acc, 0, 0, 0);
            acc = __builtin_amdgcn_mfma_f32_16x16x32_bf16(ah, bl, acc, 0, 0, 0);
            if (c < 14) { p0[cur] = n0; p1[cur] = n1; }
        }

        const int n     = lane & 15;
        const int rbase = row0 + ((lane >> 4) << 2);
#pragma unroll
        for (int i = 0; i < 4; ++i)
            xwh[(size_t)(rbase + i) * HID_DIM + n] = __float2half_rn(acc[i]);
    }
}

// ---------------------------------------------------------------------------
// g1 standalone (fallback path only)
__global__ __launch_bounds__(256) void g1_xw_mfma(const float* __restrict__ x,
                                                  const float* __restrict__ W1,
                                                  __half* __restrict__ xwh) {
    __shared__ alignas(16) unsigned short whi[16 * 64 * 8];
    __shared__ alignas(16) unsigned short wlo[16 * 64 * 8];
    const int t = threadIdx.x;

    for (int idx = t; idx < 16 * 64 * 8; idx += 256) {
        int c  = idx >> 9;
        int l  = (idx >> 3) & 63;
        int tt = idx & 7;
        int k  = c * 32 + ((l >> 4) << 3) + tt;
        int j  = l & 15;
        float w = W1[k * HID_DIM + j];
        unsigned u = __float_as_uint(w);
        float hif = __uint_as_float(u & 0xffff0000u);
        whi[idx] = (unsigned short)(u >> 16);
        wlo[idx] = bf16_rne(w - hif);
    }
    __syncthreads();

    const int lane = t & 63;
    const int wid  = blockIdx.x * 4 + (t >> 6);
    if (wid >= G1_TILES) return;
    const int row0 = wid * 16;

    const float* xrow = x + (size_t)(row0 + (lane & 15)) * IN_DIM + ((lane >> 4) << 3);
    const unsigned short* whp = &whi[lane * 8];
    const unsigned short* wlp = &wlo[lane * 8];

    f32x4 acc = {0.f, 0.f, 0.f, 0.f};
    float4 p0[2], p1[2];
    p0[0] = *(const float4*)(xrow);
    p1[0] = *(const float4*)(xrow + 4);
    p0[1] = *(const float4*)(xrow + 32);
    p1[1] = *(const float4*)(xrow + 36);
#pragma unroll
    for (int c = 0; c < 16; ++c) {
        const int cur = c & 1;
        float4 n0, n1;
        if (c < 14) {
            n0 = *(const float4*)(xrow + (c + 2) * 32);
            n1 = *(const float4*)(xrow + (c + 2) * 32 + 4);
        }
        float av[8] = {p0[cur].x, p0[cur].y, p0[cur].z, p0[cur].w,
                       p1[cur].x, p1[cur].y, p1[cur].z, p1[cur].w};
        bf16x8 ah, al;
#pragma unroll
        for (int e = 0; e < 8; ++e) {
            unsigned u = __float_as_uint(av[e]);
            ah[e] = (short)(u >> 16);
            float lof = av[e] - __uint_as_float(u & 0xffff0000u);
            al[e] = (short)bf16_rne(lof);
        }
        bf16x8 bh = *(const bf16x8*)(whp + (size_t)c * 512);
        bf16x8 bl = *(const bf16x8*)(wlp + (size_t)c * 512);
        acc = __builtin_amdgcn_mfma_f32_16x16x32_bf16(ah, bh, acc, 0, 0, 0);
        acc = __builtin_amdgcn_mfma_f32_16x16x32_bf16(al, bh, acc, 0, 0, 0);
        acc = __builtin_amdgcn_mfma_f32_16x16x32_bf16(ah, bl, acc, 0, 0, 0);
        if (c < 14) { p0[cur] = n0; p1[cur] = n1; }
    }

    const int n     = lane & 15;
    const int rbase = row0 + ((lane >> 4) << 2);
#pragma unroll
    for (int i = 0; i < 4; ++i)
        xwh[(size_t)(rbase + i) * HID_DIM + n] = __float2half_rn(acc[i]);
}

// ---------------------------------------------------------------------------
// s2p4: fused per-bucket {counting sort -> sorted LDS} + {layer-1 spmm +
// bias + relu + .W2}. (unchanged from R4/R5)
__global__ __launch_bounds__(512) void s2p4(const int* __restrict__ cursor,
                                            uint2* __restrict__ rec,
                                            int2* __restrict__ row,
                                            const __half* __restrict__ xwh,
                                            const float* __restrict__ b1,
                                            const float* __restrict__ W2,
                                            float* __restrict__ hw, int cap) {
    __shared__ uint2 srt[CAP_MAX];
    __shared__ int ocnt[128], scn[128], cur[128];
    const int t = threadIdx.x;
    const int bkt = blockIdx.x;
    const int e0 = bkt * cap;
    int n = cursor[bkt] - e0;
    n = max(0, min(n, cap));
    if (t < 128) ocnt[t] = 0;
    __syncthreads();
    // A: histogram
    for (int i = t; i < n; i += 512)
        atomicAdd(&ocnt[rec[e0 + i].x & 127u], 1);
    __syncthreads();
    // B: exclusive scan + row[]
    if (t < 128) scn[t] = ocnt[t];
    __syncthreads();
    for (int off = 1; off < 128; off <<= 1) {
        int v = 0;
        if (t < 128 && t >= off) v = scn[t - off];
        __syncthreads();
        if (t < 128 && t >= off) scn[t] += v;
        __syncthreads();
    }
    if (t < 128) {
        int b = scn[t] - ocnt[t];          // exclusive prefix
        cur[t] = b;
        int node = (bkt << BKT_SH) + t;
        if (node < N_NODES) row[node] = make_int2(e0 + b, ocnt[t]);
    }
    __syncthreads();
    // C: scatter into sorted LDS (re-read is cache-hot)
    for (int i = t; i < n; i += 512) {
        uint2 r = rec[e0 + i];
        int d = (int)(r.x & 127u);
        int pos = atomicAdd(&cur[d], 1);
        srt[pos] = make_uint2(r.x >> BKT_SH, r.y);   // (src, w)
    }
    __syncthreads();
    // D: coalesced writeback for p5
    for (int i = t; i < n; i += 512) rec[e0 + i] = srt[i];
    // E: layer-1 from sorted LDS, register accumulation
    const int j = t & 15;
    for (int g = (t >> 4); g < 128; g += 32) {
        const int node = (bkt << BKT_SH) + g;
        if (node >= N_NODES) continue;
        int e = scn[g] - ocnt[g];
        const int end = scn[g];
        float acc = 0.0f;
        for (; e + 4 <= end; e += 4) {
            uint2 q0 = srt[e], q1 = srt[e + 1], q2 = srt[e + 2], q3 = srt[e + 3];
            float f0 = __half2float(xwh[(size_t)q0.x * HID_DIM + j]);
            float f1 = __half2float(xwh[(size_t)q1.x * HID_DIM + j]);
            float f2 = __half2float(xwh[(size_t)q2.x * HID_DIM + j]);
            float f3 = __half2float(xwh[(size_t)q3.x * HID_DIM + j]);
            acc += __uint_as_float(q0.y) * f0;
            acc += __uint_as_float(q1.y) * f1;
            acc += __uint_as_float(q2.y) * f2;
            acc += __uint_as_float(q3.y) * f3;
        }
        for (; e < end; ++e) {
            uint2 q = srt[e];
            acc += __uint_as_float(q.y) * __half2float(xwh[(size_t)q.x * HID_DIM + j]);
        }
        float v = fmaxf(acc + b1[j], 0.0f) * W2[j];
        v += __shfl_xor(v, 1);
        v += __shfl_xor(v, 2);
        v += __shfl_xor(v, 4);
        v += __shfl_xor(v, 8);
        if (j == 0) hw[node] = v;
    }
}

// ---------------------------------------------------------------------------
// p5: spmm2 over the sorted records; 8 lanes/node, coalesced rec reads.
__global__ __launch_bounds__(256) void p5_layer2(const int2* __restrict__ row,
                                                 const uint2* __restrict__ rec,
                                                 const float* __restrict__ hwv,
                                                 const float* __restrict__ b2,
                                                 float* __restrict__ out) {
    const int t = threadIdx.x;
    const int node = blockIdx.x * 32 + (t >> 3);
    const int i = t & 7;
    int2 r = row[node];
    const int end = r.x + r.y;
    int k = r.x + i;
    float s = 0.0f;
    for (; k + 24 < end; k += 32) {
        uint2 a = rec[k], b = rec[k + 8], c = rec[k + 16], d = rec[k + 24];
        float ha = hwv[a.x], hb = hwv[b.x], hc = hwv[c.x], hd = hwv[d.x];
        s += __uint_as_float(a.y) * ha + __uint_as_float(b.y) * hb
           + __uint_as_float(c.y) * hc + __uint_as_float(d.y) * hd;
    }
    for (; k < end; k += 8) {
        uint2 a = rec[k];
        s += __uint_as_float(a.y) * hwv[a.x];
    }
    s += __shfl_xor(s, 1);
    s += __shfl_xor(s, 2);
    s += __shfl_xor(s, 4);
    if (i == 0) out[node] = b2[0] + s;
}

// ---------------------------------------------------------------------------
// fallback path (atomic scatter) if workspace is too small
// ---------------------------------------------------------------------------
__global__ void f0_zero(float* __restrict__ h, const float* __restrict__ b2,
                        float* __restrict__ out) {
    int i = blockIdx.x * blockDim.x + threadIdx.x;
    if (i < N_NODES * HID_DIM) h[i] = 0.0f;
    if (i < N_NODES) out[i] = b2[0];
}
__global__ void k2_spmm1(const int* __restrict__ src, const int* __restrict__ dst,
                         const float* __restrict__ wgt, const __half* __restrict__ xwh,
                         float* __restrict__ h) {
    int t = blockIdx.x * blockDim.x + threadIdx.x;
    int e = t >> 4;
    int j = t & (HID_DIM - 1);
    if (e < N_EDGES) {
        float v = wgt[e] * __half2float(xwh[(size_t)src[e] * HID_DIM + j]);
        atomic_add_f32(&h[(size_t)dst[e] * HID_DIM + j], v);
    }
}
__global__ void k3_act(const float* __restrict__ h, const float* __restrict__ b1,
                       const float* __restrict__ W2, float* __restrict__ hw) {
    int i = blockIdx.x * blockDim.x + threadIdx.x;
    if (i >= N_NODES) return;
    const float4* h4 = (const float4*)(h + (size_t)i * HID_DIM);
    const float4* b4 = (const float4*)b1;
    const float4* w4 = (const float4*)W2;
    float acc = 0.0f;
#pragma unroll
    for (int q = 0; q < HID_DIM / 4; ++q) {
        float4 hv = h4[q]; float4 bv = b4[q]; float4 wv = w4[q];
        acc += fmaxf(hv.x + bv.x, 0.0f) * wv.x;
        acc += fmaxf(hv.y + bv.y, 0.0f) * wv.y;
        acc += fmaxf(hv.z + bv.z, 0.0f) * wv.z;
        acc += fmaxf(hv.w + bv.w, 0.0f) * wv.w;
    }
    hw[i] = acc;
}
__global__ void k4_spmm2(const int* __restrict__ src, const int* __restrict__ dst,
                         const float* __restrict__ wgt, const float* __restrict__ hw,
                         float* __restrict__ out) {
    int e = blockIdx.x * blockDim.x + threadIdx.x;
    if (e < N_EDGES) atomic_add_f32(&out[dst[e]], wgt[e] * hw[src[e]]);
}

// ---------------------------------------------------------------------------

extern "C" void kernel_launch(void* const* d_in, const int* in_sizes, int n_in,
                              void* d_out, int out_size, void* d_ws, size_t ws_size,
                              hipStream_t stream) {
    const float* x    = (const float*)d_in[0];
    const int*   esrc = (const int*)  d_in[1];
    const int*   edst = (const int*)  d_in[2];
    const float* ew   = (const float*)d_in[3];
    const float* W1   = (const float*)d_in[4];
    const float* b1   = (const float*)d_in[5];
    const float* W2   = (const float*)d_in[6];
    const float* b2   = (const float*)d_in[7];
    float* out = (float*)d_out;
    char* ws = (char*)d_ws;

    // workspace layout
    __half* xwh    = (__half*)ws;                                  // N*16 halfs
    float*  hw     = (float*)(ws + (size_t)N_NODES * HID_DIM * 2); // N floats
    int*    cursor = (int*)(hw + N_NODES);                         // B_BKT ints
    int2*   row    = (int2*)(((size_t)(cursor + B_BKT) + 7) & ~(size_t)7); // N int2
    size_t rec_off = ((size_t)((char*)(row + N_NODES) - ws) + 15) & ~(size_t)15;
    uint2* rec = (uint2*)(ws + rec_off);

    int cap = 0;
    if (ws_size > rec_off) {
        size_t cap_fit = (ws_size - rec_off) / ((size_t)B_BKT * sizeof(uint2));
        cap = (int)(cap_fit < CAP_MAX ? cap_fit : CAP_MAX);
    }

    if (cap >= 4480) {
        z0_init<<<(B_BKT + 255) / 256, 256, 0, stream>>>(cursor, cap);
        m1_gs<<<NBLK2 + G1_BLK, 512, MERGED_SMEM, stream>>>(x, W1, xwh,
                                                            esrc, edst, ew,
                                                            cursor, rec, cap);
        s2p4<<<B_BKT, 512, 0, stream>>>(cursor, rec, row, xwh, b1, W2, hw, cap);
        p5_layer2<<<N_NODES / 32, 256, 0, stream>>>(row, rec, hw, b2, out);
    } else {
        // fallback: atomic scatter
        __half* f_xwh = (__half*)ws;
        float*  f_h   = (float*)(ws + (size_t)N_NODES * HID_DIM * 2);
        float*  f_hw  = f_h + (size_t)N_NODES * HID_DIM;
        int n = N_NODES * HID_DIM;
        f0_zero<<<(n + 255) / 256, 256, 0, stream>>>(f_h, b2, out);
        g1_xw_mfma<<<(G1_TILES + 3) / 4, 256, 0, stream>>>(x, W1, f_xwh);
        k2_spmm1<<<(N_EDGES * 16) / 256, 256, 0, stream>>>(esrc, edst, ew, f_xwh, f_h);
        k3_act<<<(N_NODES + 255) / 256, 256, 0, stream>>>(f_h, b1, W2, f_hw);
        k4_spmm2<<<(N_EDGES + 255) / 256, 256, 0, stream>>>(esrc, edst, ew, f_hw, out);
    }
}